// Round 3
// baseline (38.135 us; speedup 1.0000x reference)
//
#include <hip/hip_runtime.h>

#define TT 65536          // total tokens = 8 * 8192
#define HDIM 512
#define NE 4
#define SEQL 8192
#define TPB 64            // tokens per block
#define NBLK (TT / TPB)   // 1024 blocks
#define BPB (SEQL / TPB)  // 128 blocks per batch
#define TPW 16            // tokens per wave
#define EPS 1e-3f         // 500x the fp32 tree-reduction error bound (~2e-6)

// One wave per token: 64 lanes x 2 float4 = 512 floats.
// fp32 logits everywhere; fp64 recompute only when top-k margins < EPS
// (~0.2% of tokens, wave-uniform branch) so indices match the np float64
// reference ordering exactly. Reduction: reduce-scatter (masks 1,2) ->
// tree (4,8,16,32) -> allgather via 3 shuffles. No LDS in the main loop.
__global__ __launch_bounds__(256, 4) void moe_gate_main(
    const float* __restrict__ x, const float* __restrict__ w,
    float* __restrict__ out, float* __restrict__ ws)
{
  const int lane = threadIdx.x & 63;
  const int wave = threadIdx.x >> 6;
  const int b0 = lane & 1;
  const int b1 = (lane >> 1) & 1;

  // fp32 weight fragments: w[e][4*lane..+3], w[e][256+4*lane..+3]  (32 VGPRs)
  float4 wA[NE], wB[NE];
#pragma unroll
  for (int e = 0; e < NE; ++e) {
    wA[e] = *(const float4*)(w + e * HDIM + 4 * lane);
    wB[e] = *(const float4*)(w + e * HDIM + 256 + 4 * lane);
  }

  float ssum[NE] = {0.f, 0.f, 0.f, 0.f};
  float cnt[NE]  = {0.f, 0.f, 0.f, 0.f};

  const int t0 = blockIdx.x * TPB + wave * TPW;
  const float4* xp = (const float4*)x;
  const size_t base = (size_t)t0 * (HDIM / 4);

  // 2-token-deep prefetch
  float4 cA = xp[base + lane],       cB = xp[base + 64 + lane];
  float4 dA = xp[base + 128 + lane], dB = xp[base + 192 + lane];

  for (int i = 0; i < TPW; ++i) {
    float4 eA, eB;
    if (i + 2 < TPW) {
      const size_t nb = base + (size_t)(i + 2) * (HDIM / 4);
      eA = xp[nb + lane];
      eB = xp[nb + 64 + lane];
    }

    // fp32 per-lane partials, 8 elems x 4 experts
    float pe[NE];
#pragma unroll
    for (int e = 0; e < NE; ++e) {
      float s = cA.x * wA[e].x;
      s = fmaf(cA.y, wA[e].y, s);
      s = fmaf(cA.z, wA[e].z, s);
      s = fmaf(cA.w, wA[e].w, s);
      s = fmaf(cB.x, wB[e].x, s);
      s = fmaf(cB.y, wB[e].y, s);
      s = fmaf(cB.z, wB[e].z, s);
      s = fmaf(cB.w, wB[e].w, s);
      pe[e] = s;
    }

    // reduce-scatter: mask 1 (keep experts 2b0,2b0+1), mask 2 (keep em=2b0+b1)
    const float s0 = (b0 ? pe[2] : pe[0]) + __shfl_xor(b0 ? pe[0] : pe[2], 1, 64);
    const float s1 = (b0 ? pe[3] : pe[1]) + __shfl_xor(b0 ? pe[1] : pe[3], 1, 64);
    float v = (b1 ? s1 : s0) + __shfl_xor(b1 ? s0 : s1, 2, 64);
    // tree across the 16 groups
    v += __shfl_xor(v, 4, 64);
    v += __shfl_xor(v, 8, 64);
    v += __shfl_xor(v, 16, 64);
    v += __shfl_xor(v, 32, 64);
    // allgather: lane^1 -> em^2, lane^2 -> em^1, lane^3 -> em^3
    const float T2 = __shfl_xor(v, 1, 64);
    const float T1 = __shfl_xor(v, 2, 64);
    const float T3 = __shfl_xor(v, 3, 64);

    // acc[j] = S_{j ^ em}, S = {v, T1, T2, T3}; select by (b0,b1)
    float acc[NE];
    acc[0] = b0 ? (b1 ? T3 : T2) : (b1 ? T1 : v);
    acc[1] = b0 ? (b1 ? T2 : T3) : (b1 ? v  : T1);
    acc[2] = b0 ? (b1 ? T1 : v)  : (b1 ? T3 : T2);
    acc[3] = b0 ? (b1 ? v  : T1) : (b1 ? T2 : T3);

    // top-1/top-2/top-3 values; strict '>' ascending = lowest-index tie-break
    int i0 = 0; float v0 = acc[0];
#pragma unroll
    for (int e = 1; e < NE; ++e) { if (acc[e] > v0) { v0 = acc[e]; i0 = e; } }
    int i1 = -1; float v1 = -3.4e38f;
#pragma unroll
    for (int e = 0; e < NE; ++e) { if (e != i0 && acc[e] > v1) { v1 = acc[e]; i1 = e; } }
    float v2 = -3.4e38f;
#pragma unroll
    for (int e = 0; e < NE; ++e) { if (e != i0 && e != i1 && acc[e] > v2) v2 = acc[e]; }

    // near-tie? (wave-uniform: butterfly logits are bitwise-identical on all lanes)
    const int risky = ((v0 - v1) < EPS) | ((v1 - v2) < EPS);
    if (__builtin_amdgcn_readfirstlane(risky)) {
      // fp64 recompute of the 4 logits (rare: ~0.2% of tokens)
      const float xe[8] = {cA.x, cA.y, cA.z, cA.w, cB.x, cB.y, cB.z, cB.w};
      float wef[NE][8];
#pragma unroll
      for (int e = 0; e < NE; ++e) {
        wef[e][0] = wA[e].x; wef[e][1] = wA[e].y; wef[e][2] = wA[e].z; wef[e][3] = wA[e].w;
        wef[e][4] = wB[e].x; wef[e][5] = wB[e].y; wef[e][6] = wB[e].z; wef[e][7] = wB[e].w;
      }
      double q[NE];
#pragma unroll
      for (int e = 0; e < NE; ++e) {
        double a = 0.0;
#pragma unroll
        for (int j = 0; j < 8; ++j) a += (double)xe[j] * (double)wef[e][j];
        q[e] = a;
      }
      const double t0d = (b0 ? q[2] : q[0]) + __shfl_xor(b0 ? q[0] : q[2], 1, 64);
      const double t1d = (b0 ? q[3] : q[1]) + __shfl_xor(b0 ? q[1] : q[3], 1, 64);
      double vd = (b1 ? t1d : t0d) + __shfl_xor(b1 ? t0d : t1d, 2, 64);
      vd += __shfl_xor(vd, 4, 64);
      vd += __shfl_xor(vd, 8, 64);
      vd += __shfl_xor(vd, 16, 64);
      vd += __shfl_xor(vd, 32, 64);
      const double U2 = __shfl_xor(vd, 1, 64);
      const double U1 = __shfl_xor(vd, 2, 64);
      const double U3 = __shfl_xor(vd, 3, 64);
      double accd[NE];
      accd[0] = b0 ? (b1 ? U3 : U2) : (b1 ? U1 : vd);
      accd[1] = b0 ? (b1 ? U2 : U3) : (b1 ? vd : U1);
      accd[2] = b0 ? (b1 ? U1 : vd) : (b1 ? U3 : U2);
      accd[3] = b0 ? (b1 ? vd : U1) : (b1 ? U2 : U3);
      i0 = 0; double w0d = accd[0];
#pragma unroll
      for (int e = 1; e < NE; ++e) { if (accd[e] > w0d) { w0d = accd[e]; i0 = e; } }
      i1 = -1; double w1d = -1.0e300;
#pragma unroll
      for (int e = 0; e < NE; ++e) { if (e != i0 && accd[e] > w1d) { w1d = accd[e]; i1 = e; } }
#pragma unroll
      for (int e = 0; e < NE; ++e) acc[e] = (float)accd[e];
      v0 = (float)w0d;
    }

    // softmax in fp32
    float u[NE]; float psum = 0.f;
#pragma unroll
    for (int e = 0; e < NE; ++e) { u[e] = __expf(acc[e] - v0); psum += u[e]; }
    const float inv = 1.0f / psum;
#pragma unroll
    for (int e = 0; e < NE; ++e) ssum[e] += u[e] * inv;
#pragma unroll
    for (int e = 0; e < NE; ++e)
      cnt[e] += ((e == i0) ? 1.f : 0.f) + ((e == i1) ? 1.f : 0.f);

    const float u0 = (i0 == 0) ? u[0] : (i0 == 1) ? u[1] : (i0 == 2) ? u[2] : u[3];
    const float u1 = (i1 == 0) ? u[0] : (i1 == 1) ? u[1] : (i1 == 2) ? u[2] : u[3];
    const float pp0 = u0 * inv, pp1 = u1 * inv;
    const float denom = pp0 + pp1 + 1e-20f;
    const float w0 = pp0 / denom, w1 = pp1 / denom;

    if (lane == 0) {
      const int t = t0 + i;
      out[2 * t]     = (float)i0;
      out[2 * t + 1] = (float)i1;
      out[2 * TT + 2 * t]     = w0;
      out[2 * TT + 2 * t + 1] = w1;
    }
    cA = dA; cB = dB;
    dA = eA; dB = eB;
  }

  // deterministic block-level combine of aux partials (no atomics)
  __shared__ float part[4][8];
  if (lane == 0) {
#pragma unroll
    for (int e = 0; e < NE; ++e) { part[wave][e] = ssum[e]; part[wave][4 + e] = cnt[e]; }
  }
  __syncthreads();
  if (threadIdx.x < 8) {
    float s = 0.f;
#pragma unroll
    for (int w2 = 0; w2 < 4; ++w2) s += part[w2][threadIdx.x];
    ws[(size_t)blockIdx.x * 8 + threadIdx.x] = s;  // [0..3]=score sums, [4..7]=counts
  }
}

// Single-block reduction over 1024 block-partials (8 KB) -> aux_loss
__global__ void moe_gate_aux(const float* __restrict__ ws, float* __restrict__ out)
{
  const int j = threadIdx.x;
  double term = 0.0;
  if (j < 32) {
    const int b = j >> 2, e = j & 3;
    float ss = 0.f, cc = 0.f;
    for (int k = 0; k < BPB; ++k) {
      const float* p = ws + (size_t)(b * BPB + k) * 8;
      ss += p[e];
      cc += p[4 + e];
    }
    term = ((double)cc / 4096.0) * ((double)ss / 8192.0);
  }
  for (int m = 1; m < 64; m <<= 1) term += __shfl_xor(term, m, 64);
  if (j == 0) out[4 * TT] = (float)(0.1 * term / 8.0);
}

extern "C" void kernel_launch(void* const* d_in, const int* in_sizes, int n_in,
                              void* d_out, int out_size, void* d_ws, size_t ws_size,
                              hipStream_t stream) {
  const float* x = (const float*)d_in[0];   // [8,8192,512] fp32
  const float* w = (const float*)d_in[1];   // [4,512] fp32
  float* out = (float*)d_out;               // idx[131072] | weight[131072] | aux[1]
  float* ws  = (float*)d_ws;                // 1024 * 8 floats = 32 KB

  moe_gate_main<<<NBLK, 256, 0, stream>>>(x, w, out, ws);
  moe_gate_aux<<<1, 64, 0, stream>>>(ws, out);
}